// Round 11
// baseline (600.886 us; speedup 1.0000x reference)
//
#include <hip/hip_runtime.h>
#include <stdint.h>

// Problem constants
#define KCB 4096
#define DIM 128
#define BSZ 8
#define TLEN 3000
#define NPT 24000            // BSZ*TLEN
#define KD (KCB*DIM)         // 524288
#define BDT (BSZ*DIM*TLEN)   // 3072000

// Output layout (floats, concatenated in reference return order)
#define OFF_ZQ    0
#define OFF_CODES 3072000
#define OFF_LOSS  3096000
#define OFF_CB    3096001
#define OFF_CS    3620289
#define OFF_EA    3624385

// Big scratch lives in d_out regions that are dead until later kernels:
//   zh/zl  -> [OFF_ZQ, OFF_ZQ+3072000)  (read by mfma + ea_scatter; z_q
//                                        written by zq_loss AFTER ea_scatter)
//   cbh/cbl-> [3096004, 3620292)        (new_codebook written by finalize LAST)
#define OUT_ZH    0            // float offset; ushort[24000*128] = 1,536,000 floats
#define OUT_ZL    1536000
#define OUT_CBH   3096004      // 16B-aligned; ushort[4096*128] = 262,144 floats
#define OUT_CBL   3358148

// Workspace layout (float units) — total ~64,400 floats = 258 KB
#define WS_LOSS   0
#define WS_NTOT   1
#define WS_COUNTS 16                     // 4096
#define WS_Y2     (WS_COUNTS + 4096)     // 4096
#define WS_X2     (WS_Y2 + 4096)         // 24000
#define WS_CS0    (WS_X2 + 24000)        // 4096
#define WS_RAND   (WS_CS0 + 4096)        // uint32[4096]
#define WS_IDX    (WS_RAND + 4096)       // int32[24000]

#define EPS_CAND 2e-3f
#define CAND_MAX 16

typedef __attribute__((ext_vector_type(8))) short bf16x8;
typedef __attribute__((ext_vector_type(4))) float f32x4;
typedef __attribute__((ext_vector_type(4))) int i32x4;

__device__ __forceinline__ unsigned short f2bf(float f) {
  uint32_t u = __float_as_uint(f);
  uint32_t r = (u + 0x7FFFu + ((u >> 16) & 1u)) >> 16;   // RNE
  return (unsigned short)r;
}
__device__ __forceinline__ float bf2f(unsigned short h) {
  return __uint_as_float(((uint32_t)h) << 16);
}

// ---------------- threefry2x32-20 (JAX-compatible) ----------------
__device__ __forceinline__ void threefry2x32(uint32_t k0, uint32_t k1,
                                             uint32_t x0, uint32_t x1,
                                             uint32_t& o0, uint32_t& o1) {
  const uint32_t ks0 = k0, ks1 = k1, ks2 = k0 ^ k1 ^ 0x1BD11BDAu;
  const int r0[4] = {13, 15, 26, 6};
  const int r1[4] = {17, 29, 16, 24};
  x0 += ks0; x1 += ks1;
  #pragma unroll
  for (int i = 0; i < 5; ++i) {
    #pragma unroll
    for (int j = 0; j < 4; ++j) {
      int r = (i & 1) ? r1[j] : r0[j];
      x0 += x1;
      x1 = (x1 << r) | (x1 >> (32 - r));
      x1 ^= x0;
    }
    uint32_t ia = (uint32_t)((i + 1) % 3), ib = (uint32_t)((i + 2) % 3);
    uint32_t a = (ia == 0) ? ks0 : (ia == 1) ? ks1 : ks2;
    uint32_t b = (ib == 0) ? ks0 : (ib == 1) ? ks1 : ks2;
    x0 += a;
    x1 += b + (uint32_t)(i + 1);
  }
  o0 = x0; o1 = x1;
}

// numpy pairwise sum-of-squares, n=128: 8 accumulators, separately-rounded
// products, combine ((r0+r1)+(r2+r3))+((r4+r5)+(r6+r7)).
__device__ __forceinline__ float np_sumsq_128(const float* __restrict__ v) {
  float r[8];
  #pragma unroll
  for (int j = 0; j < 8; ++j) r[j] = __fmul_rn(v[j], v[j]);
  #pragma unroll
  for (int i = 8; i < DIM; i += 8) {
    #pragma unroll
    for (int j = 0; j < 8; ++j)
      r[j] = __fadd_rn(r[j], __fmul_rn(v[i + j], v[i + j]));
  }
  return __fadd_rn(__fadd_rn(__fadd_rn(r[0], r[1]), __fadd_rn(r[2], r[3])),
                   __fadd_rn(__fadd_rn(r[4], r[5]), __fadd_rn(r[6], r[7])));
}

// ---------------- prep_z: transpose z -> bf16 hi/lo rows + np-exact x2 -----
__global__ void prep_z_kernel(const float* __restrict__ z,
                              unsigned short* __restrict__ zh,
                              unsigned short* __restrict__ zl,
                              float* __restrict__ x2) {
  __shared__ float zt[64 * 132];
  const int tid = threadIdx.x;
  const int n0 = blockIdx.x * 64;
  {
    int nl = tid & 63, dd = tid >> 6;
    int n = n0 + nl;
    int b = n / TLEN, t = n - b * TLEN;
    const float* zbase = z + (size_t)b * (DIM * TLEN) + t;
    #pragma unroll
    for (int d = dd; d < DIM; d += 4) zt[nl * 132 + d] = zbase[(size_t)d * TLEN];
  }
  __syncthreads();
  if (tid < 64) x2[n0 + tid] = np_sumsq_128(zt + tid * 132);

  int r = tid >> 2, d0 = (tid & 3) * 32;
  const float* src = zt + r * 132 + d0;
  size_t base = (size_t)(n0 + r) * 128 + d0;
  #pragma unroll
  for (int c = 0; c < 4; ++c) {
    i32x4 wh, wl;
    #pragma unroll
    for (int q = 0; q < 4; ++q) {
      float f0 = src[c * 8 + q * 2], f1 = src[c * 8 + q * 2 + 1];
      unsigned short h0 = f2bf(f0), h1 = f2bf(f1);
      unsigned short l0 = f2bf(f0 - bf2f(h0)), l1 = f2bf(f1 - bf2f(h1));
      wh[q] = (int)((uint32_t)h0 | ((uint32_t)h1 << 16));
      wl[q] = (int)((uint32_t)l0 | ((uint32_t)l1 << 16));
    }
    *(i32x4*)(zh + base + c * 8) = wh;
    *(i32x4*)(zl + base + c * 8) = wl;
  }
}

// ---------------- prep_cb: cb -> bf16 hi/lo + np-exact y2 ----------------
__global__ void prep_cb_kernel(const float* __restrict__ cb,
                               unsigned short* __restrict__ cbh,
                               unsigned short* __restrict__ cbl,
                               float* __restrict__ y2) {
  int k = blockIdx.x * 256 + threadIdx.x;
  const float4* row4 = (const float4*)(cb + (size_t)k * DIM);
  float racc[8];
  #pragma unroll
  for (int j = 0; j < 8; ++j) racc[j] = 0.f;
  #pragma unroll 4
  for (int c2 = 0; c2 < 16; ++c2) {
    float4 a = row4[c2 * 2], b = row4[c2 * 2 + 1];
    float f[8] = {a.x, a.y, a.z, a.w, b.x, b.y, b.z, b.w};
    i32x4 wh, wl;
    #pragma unroll
    for (int q = 0; q < 4; ++q) {
      float f0 = f[q * 2], f1 = f[q * 2 + 1];
      unsigned short h0 = f2bf(f0), h1 = f2bf(f1);
      unsigned short l0 = f2bf(f0 - bf2f(h0)), l1 = f2bf(f1 - bf2f(h1));
      wh[q] = (int)((uint32_t)h0 | ((uint32_t)h1 << 16));
      wl[q] = (int)((uint32_t)l0 | ((uint32_t)l1 << 16));
    }
    *(i32x4*)(cbh + (size_t)k * DIM + c2 * 8) = wh;
    *(i32x4*)(cbl + (size_t)k * DIM + c2 * 8) = wl;
    #pragma unroll
    for (int j = 0; j < 8; ++j)
      racc[j] = __fadd_rn(racc[j], __fmul_rn(f[j], f[j]));
  }
  y2[k] = __fadd_rn(__fadd_rn(__fadd_rn(racc[0], racc[1]), __fadd_rn(racc[2], racc[3])),
                    __fadd_rn(__fadd_rn(racc[4], racc[5]), __fadd_rn(racc[6], racc[7])));
}

// ---------------- ea_init ----------------
__global__ void ea_init_kernel(const float* __restrict__ ema_ea, float* __restrict__ out_ea) {
  int i = blockIdx.x * 256 + threadIdx.x;
  out_ea[i] = 0.99f * ema_ea[i];
}

// ---------------- MFMA argmin, LDS-free two-sweep ----------------
// 750 blocks x 256 thr (4 waves). 32 n-rows/block; z B-frags live in regs
// (launch_bounds(256,3): VGPR cap ~168 so the 64-VGPR z-frag set STAYS
// register-resident — R10's bare (256) capped VGPR at 64 and spilled them
// to scratch, which was the 200us/pass floor). cb A-frags straight from L2.
__launch_bounds__(256, 3)
__global__ void mfma_argmin_kernel(const unsigned short* __restrict__ zh,
                                   const unsigned short* __restrict__ zl,
                                   const unsigned short* __restrict__ cbh,
                                   const unsigned short* __restrict__ cbl,
                                   const float* __restrict__ y2g,
                                   const float* __restrict__ x2g,
                                   const float* __restrict__ z,
                                   const float* __restrict__ cb,
                                   int* __restrict__ idx_out,
                                   float* __restrict__ codes_out) {
  __shared__ float limbuf[4 * 32];      // [wv][row]
  __shared__ int cand_cnt[32];
  __shared__ int cand_k[32 * CAND_MAX];

  const int tid = threadIdx.x;
  const int wv = tid >> 6, lane = tid & 63;
  const int lg = lane >> 4, lc = lane & 15;
  const int n0 = blockIdx.x * 32;

  // ---- z B-frags once into registers: row n0+ns*16+lc, chunk ds*4+lg
  bf16x8 zbh[2][4], zbl[2][4];
  #pragma unroll
  for (int ns = 0; ns < 2; ++ns) {
    const unsigned short* sh_ = zh + (size_t)(n0 + ns * 16 + lc) * 128 + lg * 8;
    const unsigned short* sl_ = zl + (size_t)(n0 + ns * 16 + lc) * 128 + lg * 8;
    #pragma unroll
    for (int ds = 0; ds < 4; ++ds) {
      zbh[ns][ds] = *(const bf16x8*)(sh_ + ds * 32);
      zbl[ns][ds] = *(const bf16x8*)(sl_ + ds * 32);
    }
  }

  if (tid < 32) cand_cnt[tid] = 0;

  const unsigned short* abase_h = cbh + (size_t)lc * 128 + lg * 8;
  const unsigned short* abase_l = cbl + (size_t)lc * 128 + lg * 8;

  float rowmin[2] = {3.402823466e+38f, 3.402823466e+38f};

  // =================== PASS 1: value-only row minimum ===================
  for (int rd = 0; rd < KCB / 128; ++rd) {
    const int kb = rd * 128 + wv * 32;
    f32x4 acc[2][2];
    #pragma unroll
    for (int ns = 0; ns < 2; ++ns)
      #pragma unroll
      for (int ks = 0; ks < 2; ++ks) acc[ns][ks] = 0.f;

    #pragma unroll
    for (int ds = 0; ds < 4; ++ds) {
      bf16x8 ah[2], al[2];
      #pragma unroll
      for (int ks = 0; ks < 2; ++ks) {
        size_t off = (size_t)(kb + ks * 16) * 128 + ds * 32;
        ah[ks] = *(const bf16x8*)(abase_h + off);
        al[ks] = *(const bf16x8*)(abase_l + off);
      }
      #pragma unroll
      for (int ns = 0; ns < 2; ++ns)
        #pragma unroll
        for (int ks = 0; ks < 2; ++ks) {
          acc[ns][ks] = __builtin_amdgcn_mfma_f32_16x16x32_bf16(ah[ks], zbh[ns][ds], acc[ns][ks], 0, 0, 0);
          acc[ns][ks] = __builtin_amdgcn_mfma_f32_16x16x32_bf16(ah[ks], zbl[ns][ds], acc[ns][ks], 0, 0, 0);
          acc[ns][ks] = __builtin_amdgcn_mfma_f32_16x16x32_bf16(al[ks], zbh[ns][ds], acc[ns][ks], 0, 0, 0);
        }
    }

    #pragma unroll
    for (int ks = 0; ks < 2; ++ks) {
      float4 y4 = *(const float4*)(y2g + kb + ks * 16 + lg * 4);
      #pragma unroll
      for (int ns = 0; ns < 2; ++ns) {
        float d0_ = fmaf(-2.f, acc[ns][ks][0], y4.x);
        float d1_ = fmaf(-2.f, acc[ns][ks][1], y4.y);
        float d2_ = fmaf(-2.f, acc[ns][ks][2], y4.z);
        float d3_ = fmaf(-2.f, acc[ns][ks][3], y4.w);
        rowmin[ns] = fminf(rowmin[ns], fminf(fminf(d0_, d1_), fminf(d2_, d3_)));
      }
    }
  }

  // merge row minima: across lg via shfl, across waves via LDS
  #pragma unroll
  for (int ns = 0; ns < 2; ++ns) {
    rowmin[ns] = fminf(rowmin[ns], __shfl_xor(rowmin[ns], 16));
    rowmin[ns] = fminf(rowmin[ns], __shfl_xor(rowmin[ns], 32));
  }
  if (lg == 0) {
    limbuf[wv * 32 + lc]      = rowmin[0];
    limbuf[wv * 32 + 16 + lc] = rowmin[1];
  }
  __syncthreads();

  float lim[2];
  #pragma unroll
  for (int ns = 0; ns < 2; ++ns) {
    int row = ns * 16 + lc;
    lim[ns] = fminf(fminf(limbuf[row], limbuf[32 + row]),
                    fminf(limbuf[64 + row], limbuf[96 + row])) + EPS_CAND;
  }

  // =================== PASS 2: collect candidates <= lim ===================
  for (int rd = 0; rd < KCB / 128; ++rd) {
    const int kb = rd * 128 + wv * 32;
    f32x4 acc[2][2];
    #pragma unroll
    for (int ns = 0; ns < 2; ++ns)
      #pragma unroll
      for (int ks = 0; ks < 2; ++ks) acc[ns][ks] = 0.f;

    #pragma unroll
    for (int ds = 0; ds < 4; ++ds) {
      bf16x8 ah[2], al[2];
      #pragma unroll
      for (int ks = 0; ks < 2; ++ks) {
        size_t off = (size_t)(kb + ks * 16) * 128 + ds * 32;
        ah[ks] = *(const bf16x8*)(abase_h + off);
        al[ks] = *(const bf16x8*)(abase_l + off);
      }
      #pragma unroll
      for (int ns = 0; ns < 2; ++ns)
        #pragma unroll
        for (int ks = 0; ks < 2; ++ks) {
          acc[ns][ks] = __builtin_amdgcn_mfma_f32_16x16x32_bf16(ah[ks], zbh[ns][ds], acc[ns][ks], 0, 0, 0);
          acc[ns][ks] = __builtin_amdgcn_mfma_f32_16x16x32_bf16(ah[ks], zbl[ns][ds], acc[ns][ks], 0, 0, 0);
          acc[ns][ks] = __builtin_amdgcn_mfma_f32_16x16x32_bf16(al[ks], zbh[ns][ds], acc[ns][ks], 0, 0, 0);
        }
    }

    #pragma unroll
    for (int ks = 0; ks < 2; ++ks) {
      float4 y4 = *(const float4*)(y2g + kb + ks * 16 + lg * 4);
      int kbase = kb + ks * 16 + lg * 4;
      #pragma unroll
      for (int ns = 0; ns < 2; ++ns) {
        float dv[4];
        dv[0] = fmaf(-2.f, acc[ns][ks][0], y4.x);
        dv[1] = fmaf(-2.f, acc[ns][ks][1], y4.y);
        dv[2] = fmaf(-2.f, acc[ns][ks][2], y4.z);
        dv[3] = fmaf(-2.f, acc[ns][ks][3], y4.w);
        float m = fminf(fminf(dv[0], dv[1]), fminf(dv[2], dv[3]));
        if (m <= lim[ns]) {
          int rowid = ns * 16 + lc;
          #pragma unroll
          for (int q = 0; q < 4; ++q) {
            if (dv[q] <= lim[ns]) {
              int pos = atomicAdd(&cand_cnt[rowid], 1);
              if (pos < CAND_MAX) cand_k[rowid * CAND_MAX + pos] = kbase + q;
            }
          }
        }
      }
    }
  }
  __syncthreads();

  // ---- tail: per-row candidate sort + exact rescore when needed
  if (tid < 32) {
    int n = n0 + tid;
    int cnt = cand_cnt[tid];
    if (cnt > CAND_MAX) cnt = CAND_MAX;
    int ci[CAND_MAX];
    for (int c = 0; c < cnt; ++c) {
      int x = cand_k[tid * CAND_MAX + c];
      int p = c;
      while (p > 0 && ci[p - 1] > x) { ci[p] = ci[p - 1]; --p; }
      ci[p] = x;
    }
    int kbest = ci[0];
    if (cnt > 1) {
      int b = n / TLEN, t = n - b * TLEN;
      const float* zr = z + (size_t)b * (DIM * TLEN) + t;
      float bestv = 0.f;
      for (int c = 0; c < cnt; ++c) {
        int k = ci[c];
        const float* cr = cb + (size_t)k * DIM;
        float dot = 0.f;
        for (int d = 0; d < DIM; ++d)
          dot = __fmaf_rn(zr[(size_t)d * TLEN], cr[d], dot);
        float tt = __fadd_rn(x2g[n], y2g[k]);
        float dist = __fsub_rn(tt, __fmul_rn(2.0f, dot));
        if (c == 0 || dist < bestv) { bestv = dist; kbest = k; }
      }
    }
    idx_out[n] = kbest;
    codes_out[n] = (float)kbest;
  }
}

// ---------------- ea_scatter: one WAVE per row n — coalesced EA atomics ----
__global__ void ea_scatter_kernel(const unsigned short* __restrict__ zh,
                                  const unsigned short* __restrict__ zl,
                                  const int* __restrict__ idx,
                                  float* __restrict__ ea_out,
                                  float* __restrict__ counts) {
  int n = (blockIdx.x * 256 + threadIdx.x) >> 6;   // wave id == row
  int lane = threadIdx.x & 63;
  int k = idx[n];
  uint32_t h = *(const uint32_t*)(zh + (size_t)n * 128 + lane * 2);
  uint32_t l = *(const uint32_t*)(zl + (size_t)n * 128 + lane * 2);
  float f0 = bf2f((unsigned short)(h & 0xffffu)) + bf2f((unsigned short)(l & 0xffffu));
  float f1 = bf2f((unsigned short)(h >> 16)) + bf2f((unsigned short)(l >> 16));
  float* dst = ea_out + (size_t)k * DIM + lane * 2;
  atomicAdd(dst, 0.01f * f0);
  atomicAdd(dst + 1, 0.01f * f1);
  if (lane == 0) atomicAdd(counts + k, 1.0f);
}

// ---------------- zq_loss: coalesced z_q gather + commit-loss ----------------
__global__ void zq_loss_kernel(const float* __restrict__ z, const float* __restrict__ cb,
                               const int* __restrict__ idx,
                               float* __restrict__ zq_out, float* __restrict__ loss_ws) {
  int i = blockIdx.x * 256 + threadIdx.x;   // [B][D][T]
  int t = i % TLEN;
  int bd = i / TLEN;
  int d = bd & (DIM - 1);
  int b = bd >> 7;
  int n = b * TLEN + t;
  int k = idx[n];
  float zv = z[i];
  float q = cb[(size_t)k * DIM + d];
  zq_out[i] = q;
  float diff = zv - q;
  float sq = diff * diff;
  #pragma unroll
  for (int m = 1; m <= 32; m <<= 1) sq += __shfl_xor(sq, m);
  __shared__ float ps[4];
  if ((threadIdx.x & 63) == 0) ps[threadIdx.x >> 6] = sq;
  __syncthreads();
  if (threadIdx.x == 0) atomicAdd(loss_ws, ps[0] + ps[1] + ps[2] + ps[3]);
}

// ---------------- cs_rand ----------------
__global__ void cs_rand_kernel(const float* __restrict__ ema_cs, const float* __restrict__ counts,
                               float* __restrict__ cs0, uint32_t* __restrict__ rnd,
                               float* __restrict__ ntot) {
  int k = blockIdx.x * 256 + threadIdx.x;
  float v = 0.99f * ema_cs[k] + 0.01f * counts[k];
  cs0[k] = v;

  uint32_t o0, o1;
  threefry2x32(0u, 42u, 0u, (uint32_t)k, o0, o1);
  uint32_t bits = o0 ^ o1;
  uint32_t hi = bits >> 16, lo = bits & 0xffffu;
  const uint32_t span = 24000u, mult = 23296u;  // 2^32 % 24000
  uint32_t off = ((hi % span) * mult + (lo % span)) % span;
  rnd[k] = off;

  float s = v;
  #pragma unroll
  for (int m = 1; m <= 32; m <<= 1) s += __shfl_xor(s, m);
  __shared__ float ps[4];
  if ((threadIdx.x & 63) == 0) ps[threadIdx.x >> 6] = s;
  __syncthreads();
  if (threadIdx.x == 0) atomicAdd(ntot, ps[0] + ps[1] + ps[2] + ps[3]);
}

// ---------------- finalize ----------------
__global__ void finalize_kernel(const float* __restrict__ z, const float* __restrict__ cs0_ws,
                                const uint32_t* __restrict__ rnd,
                                const float* __restrict__ ntot_ws, const float* __restrict__ loss_ws,
                                float* __restrict__ out) {
  int i = blockIdx.x * 256 + threadIdx.x;   // i < KD
  int k = i >> 7, d = i & (DIM - 1);
  float cs0 = cs0_ws[k];
  float ntot = *ntot_ws;
  float* ea = out + OFF_EA;
  float ea0 = ea[i];
  float csz = (cs0 + 1e-5f) / (ntot + (float)KCB * 1e-5f) * ntot;
  float embed = ea0 / fmaxf(csz, 1e-12f);
  bool dead = cs0 < 2.0f;
  uint32_t rn = rnd[k];
  int bb = (int)(rn / TLEN), tt = (int)(rn % TLEN);
  float sampled = z[(size_t)bb * (DIM * TLEN) + (size_t)d * TLEN + tt];
  out[OFF_CB + i] = dead ? sampled : embed;
  ea[i] = dead ? sampled : ea0;
  if (d == 0) out[OFF_CS + k] = dead ? 1.0f : cs0;
  if (i == 0) out[OFF_LOSS] = (*loss_ws) * (1.0f / (float)BDT);
}

extern "C" void kernel_launch(void* const* d_in, const int* in_sizes, int n_in,
                              void* d_out, int out_size, void* d_ws, size_t ws_size,
                              hipStream_t stream) {
  const float* z      = (const float*)d_in[0];
  const float* cb     = (const float*)d_in[1];
  const float* ema_cs = (const float*)d_in[2];
  const float* ema_ea = (const float*)d_in[3];
  float* out = (float*)d_out;
  float* wsf = (float*)d_ws;

  unsigned short* zh  = (unsigned short*)(out + OUT_ZH);
  unsigned short* zl  = (unsigned short*)(out + OUT_ZL);
  unsigned short* cbh = (unsigned short*)(out + OUT_CBH);
  unsigned short* cbl = (unsigned short*)(out + OUT_CBL);

  hipMemsetAsync(d_ws, 0, (size_t)(16 + 4096) * sizeof(float), stream);

  prep_cb_kernel<<<KCB / 256, 256, 0, stream>>>(cb, cbh, cbl, wsf + WS_Y2);
  prep_z_kernel<<<NPT / 64, 256, 0, stream>>>(z, zh, zl, wsf + WS_X2);
  ea_init_kernel<<<KD / 256, 256, 0, stream>>>(ema_ea, out + OFF_EA);

  mfma_argmin_kernel<<<NPT / 32, 256, 0, stream>>>(zh, zl, cbh, cbl,
                                                   wsf + WS_Y2, wsf + WS_X2,
                                                   z, cb,
                                                   (int*)(wsf + WS_IDX), out + OFF_CODES);

  // ea_scatter reads zh/zl (z_q region) -> MUST run before zq_loss overwrites it
  ea_scatter_kernel<<<NPT * 64 / 256, 256, 0, stream>>>(zh, zl, (int*)(wsf + WS_IDX),
                                                        out + OFF_EA, wsf + WS_COUNTS);
  zq_loss_kernel<<<BDT / 256, 256, 0, stream>>>(z, cb, (int*)(wsf + WS_IDX),
                                                out + OFF_ZQ, wsf + WS_LOSS);
  cs_rand_kernel<<<KCB / 256, 256, 0, stream>>>(ema_cs, wsf + WS_COUNTS,
                                                wsf + WS_CS0, (uint32_t*)(wsf + WS_RAND),
                                                wsf + WS_NTOT);
  finalize_kernel<<<KD / 256, 256, 0, stream>>>(z, wsf + WS_CS0, (uint32_t*)(wsf + WS_RAND),
                                                wsf + WS_NTOT, wsf + WS_LOSS, out);
}

// Round 12
// 306.649 us; speedup vs baseline: 1.9595x; 1.9595x over previous
//
#include <hip/hip_runtime.h>
#include <stdint.h>

// Problem constants
#define KCB 4096
#define DIM 128
#define BSZ 8
#define TLEN 3000
#define NPT 24000            // BSZ*TLEN
#define KD (KCB*DIM)         // 524288
#define BDT (BSZ*DIM*TLEN)   // 3072000

// Output layout (floats, concatenated in reference return order)
#define OFF_ZQ    0
#define OFF_CODES 3072000
#define OFF_LOSS  3096000
#define OFF_CB    3096001
#define OFF_CS    3620289
#define OFF_EA    3624385

// Big scratch lives in d_out regions that are dead until later kernels:
//   zh/zl  -> [OFF_ZQ, OFF_ZQ+3072000)  (read by mfma + ea_scatter; z_q
//                                        written by zq_loss AFTER ea_scatter)
//   cbh/cbl-> [3096004, 3620292)        (new_codebook written by finalize LAST)
#define OUT_ZH    0            // float offset; ushort[24000*128] = 1,536,000 floats
#define OUT_ZL    1536000
#define OUT_CBH   3096004      // 16B-aligned; ushort[4096*128] = 262,144 floats
#define OUT_CBL   3358148

// Workspace layout (float units) — total ~64,400 floats = 258 KB
#define WS_LOSS   0
#define WS_NTOT   1
#define WS_COUNTS 16                     // 4096
#define WS_Y2     (WS_COUNTS + 4096)     // 4096
#define WS_X2     (WS_Y2 + 4096)         // 24000
#define WS_CS0    (WS_X2 + 24000)        // 4096
#define WS_RAND   (WS_CS0 + 4096)        // uint32[4096]
#define WS_IDX    (WS_RAND + 4096)       // int32[24000]

#define EPS_CAND 2e-3f
#define CAND_MAX 8

typedef __attribute__((ext_vector_type(8))) short bf16x8;
typedef __attribute__((ext_vector_type(4))) float f32x4;
typedef __attribute__((ext_vector_type(4))) int i32x4;

__device__ __forceinline__ unsigned short f2bf(float f) {
  uint32_t u = __float_as_uint(f);
  uint32_t r = (u + 0x7FFFu + ((u >> 16) & 1u)) >> 16;   // RNE
  return (unsigned short)r;
}
__device__ __forceinline__ float bf2f(unsigned short h) {
  return __uint_as_float(((uint32_t)h) << 16);
}

// ---------------- threefry2x32-20 (JAX-compatible) ----------------
__device__ __forceinline__ void threefry2x32(uint32_t k0, uint32_t k1,
                                             uint32_t x0, uint32_t x1,
                                             uint32_t& o0, uint32_t& o1) {
  const uint32_t ks0 = k0, ks1 = k1, ks2 = k0 ^ k1 ^ 0x1BD11BDAu;
  const int r0[4] = {13, 15, 26, 6};
  const int r1[4] = {17, 29, 16, 24};
  x0 += ks0; x1 += ks1;
  #pragma unroll
  for (int i = 0; i < 5; ++i) {
    #pragma unroll
    for (int j = 0; j < 4; ++j) {
      int r = (i & 1) ? r1[j] : r0[j];
      x0 += x1;
      x1 = (x1 << r) | (x1 >> (32 - r));
      x1 ^= x0;
    }
    uint32_t ia = (uint32_t)((i + 1) % 3), ib = (uint32_t)((i + 2) % 3);
    uint32_t a = (ia == 0) ? ks0 : (ia == 1) ? ks1 : ks2;
    uint32_t b = (ib == 0) ? ks0 : (ib == 1) ? ks1 : ks2;
    x0 += a;
    x1 += b + (uint32_t)(i + 1);
  }
  o0 = x0; o1 = x1;
}

// numpy pairwise sum-of-squares, n=128
__device__ __forceinline__ float np_sumsq_128(const float* __restrict__ v) {
  float r[8];
  #pragma unroll
  for (int j = 0; j < 8; ++j) r[j] = __fmul_rn(v[j], v[j]);
  #pragma unroll
  for (int i = 8; i < DIM; i += 8) {
    #pragma unroll
    for (int j = 0; j < 8; ++j)
      r[j] = __fadd_rn(r[j], __fmul_rn(v[i + j], v[i + j]));
  }
  return __fadd_rn(__fadd_rn(__fadd_rn(r[0], r[1]), __fadd_rn(r[2], r[3])),
                   __fadd_rn(__fadd_rn(r[4], r[5]), __fadd_rn(r[6], r[7])));
}

// ---------------- prep_z: transpose z -> bf16 hi/lo rows + np-exact x2 -----
__global__ void prep_z_kernel(const float* __restrict__ z,
                              unsigned short* __restrict__ zh,
                              unsigned short* __restrict__ zl,
                              float* __restrict__ x2) {
  __shared__ float zt[64 * 132];
  const int tid = threadIdx.x;
  const int n0 = blockIdx.x * 64;
  {
    int nl = tid & 63, dd = tid >> 6;
    int n = n0 + nl;
    int b = n / TLEN, t = n - b * TLEN;
    const float* zbase = z + (size_t)b * (DIM * TLEN) + t;
    #pragma unroll
    for (int d = dd; d < DIM; d += 4) zt[nl * 132 + d] = zbase[(size_t)d * TLEN];
  }
  __syncthreads();
  if (tid < 64) x2[n0 + tid] = np_sumsq_128(zt + tid * 132);

  int r = tid >> 2, d0 = (tid & 3) * 32;
  const float* src = zt + r * 132 + d0;
  size_t base = (size_t)(n0 + r) * 128 + d0;
  #pragma unroll
  for (int c = 0; c < 4; ++c) {
    i32x4 wh, wl;
    #pragma unroll
    for (int q = 0; q < 4; ++q) {
      float f0 = src[c * 8 + q * 2], f1 = src[c * 8 + q * 2 + 1];
      unsigned short h0 = f2bf(f0), h1 = f2bf(f1);
      unsigned short l0 = f2bf(f0 - bf2f(h0)), l1 = f2bf(f1 - bf2f(h1));
      wh[q] = (int)((uint32_t)h0 | ((uint32_t)h1 << 16));
      wl[q] = (int)((uint32_t)l0 | ((uint32_t)l1 << 16));
    }
    *(i32x4*)(zh + base + c * 8) = wh;
    *(i32x4*)(zl + base + c * 8) = wl;
  }
}

// ---------------- prep_cb: cb -> bf16 hi/lo + np-exact y2 ----------------
__global__ void prep_cb_kernel(const float* __restrict__ cb,
                               unsigned short* __restrict__ cbh,
                               unsigned short* __restrict__ cbl,
                               float* __restrict__ y2) {
  int k = blockIdx.x * 256 + threadIdx.x;
  const float4* row4 = (const float4*)(cb + (size_t)k * DIM);
  float racc[8];
  #pragma unroll
  for (int j = 0; j < 8; ++j) racc[j] = 0.f;
  #pragma unroll 4
  for (int c2 = 0; c2 < 16; ++c2) {
    float4 a = row4[c2 * 2], b = row4[c2 * 2 + 1];
    float f[8] = {a.x, a.y, a.z, a.w, b.x, b.y, b.z, b.w};
    i32x4 wh, wl;
    #pragma unroll
    for (int q = 0; q < 4; ++q) {
      float f0 = f[q * 2], f1 = f[q * 2 + 1];
      unsigned short h0 = f2bf(f0), h1 = f2bf(f1);
      unsigned short l0 = f2bf(f0 - bf2f(h0)), l1 = f2bf(f1 - bf2f(h1));
      wh[q] = (int)((uint32_t)h0 | ((uint32_t)h1 << 16));
      wl[q] = (int)((uint32_t)l0 | ((uint32_t)l1 << 16));
    }
    *(i32x4*)(cbh + (size_t)k * DIM + c2 * 8) = wh;
    *(i32x4*)(cbl + (size_t)k * DIM + c2 * 8) = wl;
    #pragma unroll
    for (int j = 0; j < 8; ++j)
      racc[j] = __fadd_rn(racc[j], __fmul_rn(f[j], f[j]));
  }
  y2[k] = __fadd_rn(__fadd_rn(__fadd_rn(racc[0], racc[1]), __fadd_rn(racc[2], racc[3])),
                    __fadd_rn(__fadd_rn(racc[4], racc[5]), __fadd_rn(racc[6], racc[7])));
}

// ---------------- ea_init ----------------
__global__ void ea_init_kernel(const float* __restrict__ ema_ea, float* __restrict__ out_ea) {
  int i = blockIdx.x * 256 + threadIdx.x;
  out_ea[i] = 0.99f * ema_ea[i];
}

// ---------------- MFMA argmin: single sweep, LDS-free, reg-dbuf ----------
// 750 blocks x 256 thr (4 waves), 32 n/block. z B-frags pinned in regs via
// asm "+v" (defeats compiler rematerialization — R10/R11's VGPR=64 trap).
// Per round each wave covers 16 k: 8 A-loads (explicit 2-deep reg double
// buffer + sched_barrier so loads issue a full round early), 24 MFMA
// (3-term bf16-split, same math/order as R8-green). Per-lane top-3 over
// individual k -> candidates within EPS -> exact np-fp32 rescore.
__launch_bounds__(256, 2)
__global__ void mfma_argmin_kernel(const unsigned short* __restrict__ zh,
                                   const unsigned short* __restrict__ zl,
                                   const unsigned short* __restrict__ cbh,
                                   const unsigned short* __restrict__ cbl,
                                   const float* __restrict__ y2g,
                                   const float* __restrict__ x2g,
                                   const float* __restrict__ z,
                                   const float* __restrict__ cb,
                                   int* __restrict__ idx_out,
                                   float* __restrict__ codes_out) {
  __shared__ float tv[32 * 48];
  __shared__ int   ti[32 * 48];

  const int tid = threadIdx.x;
  const int wv = tid >> 6, lane = tid & 63;
  const int lg = lane >> 4, lc = lane & 15;
  const int n0 = blockIdx.x * 32;

  // ---- z B-frags once into registers: row n0+ns*16+lc, chunk ds*4+lg
  bf16x8 zbh[2][4], zbl[2][4];
  #pragma unroll
  for (int ns = 0; ns < 2; ++ns) {
    const unsigned short* sh_ = zh + (size_t)(n0 + ns * 16 + lc) * 128 + lg * 8;
    const unsigned short* sl_ = zl + (size_t)(n0 + ns * 16 + lc) * 128 + lg * 8;
    #pragma unroll
    for (int ds = 0; ds < 4; ++ds) {
      zbh[ns][ds] = *(const bf16x8*)(sh_ + ds * 32);
      zbl[ns][ds] = *(const bf16x8*)(sl_ + ds * 32);
    }
  }
  // pin: opaque writer -> compiler cannot rematerialize the loads per-round
  #pragma unroll
  for (int ns = 0; ns < 2; ++ns)
    #pragma unroll
    for (int ds = 0; ds < 4; ++ds)
      asm volatile("" : "+v"(zbh[ns][ds]), "+v"(zbl[ns][ds]));

  const unsigned short* ahb = cbh + (size_t)(wv * 16 + lc) * 128 + lg * 8;
  const unsigned short* alb = cbl + (size_t)(wv * 16 + lc) * 128 + lg * 8;

  float t1v[2], t2v[2], t3v[2];
  int   t1i[2], t2i[2], t3i[2];
  #pragma unroll
  for (int ns = 0; ns < 2; ++ns) {
    t1v[ns] = t2v[ns] = t3v[ns] = 3.402823466e+38f;
    t1i[ns] = t2i[ns] = t3i[ns] = 0x7FFFFFFF;
  }

  bf16x8 a0h[4], a0l[4], a1h[4], a1l[4];
  #pragma unroll
  for (int ds = 0; ds < 4; ++ds) {
    a0h[ds] = *(const bf16x8*)(ahb + ds * 32);
    a0l[ds] = *(const bf16x8*)(alb + ds * 32);
  }

  // per-round body: 24 MFMA + distances + top-3 insert (R8-identical math)
  auto body = [&](bf16x8 (&ah)[4], bf16x8 (&al)[4], int rd) {
    const int kb = rd * 64 + wv * 16;
    f32x4 acc[2];
    acc[0] = 0.f; acc[1] = 0.f;
    #pragma unroll
    for (int ds = 0; ds < 4; ++ds)
      #pragma unroll
      for (int ns = 0; ns < 2; ++ns) {
        acc[ns] = __builtin_amdgcn_mfma_f32_16x16x32_bf16(ah[ds], zbh[ns][ds], acc[ns], 0, 0, 0);
        acc[ns] = __builtin_amdgcn_mfma_f32_16x16x32_bf16(ah[ds], zbl[ns][ds], acc[ns], 0, 0, 0);
        acc[ns] = __builtin_amdgcn_mfma_f32_16x16x32_bf16(al[ds], zbh[ns][ds], acc[ns], 0, 0, 0);
      }
    float4 y4 = *(const float4*)(y2g + kb + lg * 4);
    int kbase = kb + lg * 4;
    #pragma unroll
    for (int ns = 0; ns < 2; ++ns) {
      float dv[4];
      dv[0] = fmaf(-2.f, acc[ns][0], y4.x);
      dv[1] = fmaf(-2.f, acc[ns][1], y4.y);
      dv[2] = fmaf(-2.f, acc[ns][2], y4.z);
      dv[3] = fmaf(-2.f, acc[ns][3], y4.w);
      #pragma unroll
      for (int q = 0; q < 4; ++q) {
        float v = dv[q];
        int kidx = kbase + q;
        bool c1 = v < t1v[ns], c2 = v < t2v[ns], c3 = v < t3v[ns];
        float n3v = c2 ? t2v[ns] : (c3 ? v : t3v[ns]);
        int   n3i = c2 ? t2i[ns] : (c3 ? kidx : t3i[ns]);
        float n2v = c1 ? t1v[ns] : (c2 ? v : t2v[ns]);
        int   n2i = c1 ? t1i[ns] : (c2 ? kidx : t2i[ns]);
        t1v[ns] = c1 ? v : t1v[ns]; t1i[ns] = c1 ? kidx : t1i[ns];
        t2v[ns] = n2v; t2i[ns] = n2i;
        t3v[ns] = n3v; t3i[ns] = n3i;
      }
    }
  };

  for (int rd = 0; rd < 64; rd += 2) {
    {  // prefetch round rd+1 into a1 (issue before a0's MFMAs)
      size_t o = (size_t)(rd + 1) * 8192;   // 64 rows * 128
      #pragma unroll
      for (int ds = 0; ds < 4; ++ds) {
        a1h[ds] = *(const bf16x8*)(ahb + o + ds * 32);
        a1l[ds] = *(const bf16x8*)(alb + o + ds * 32);
      }
    }
    __builtin_amdgcn_sched_barrier(0);
    body(a0h, a0l, rd);
    {  // prefetch round rd+2 into a0 (rd=62 -> row 4096 = cbl start, valid mem, unused)
      size_t o = (size_t)(rd + 2) * 8192;
      #pragma unroll
      for (int ds = 0; ds < 4; ++ds) {
        a0h[ds] = *(const bf16x8*)(ahb + o + ds * 32);
        a0l[ds] = *(const bf16x8*)(alb + o + ds * 32);
      }
    }
    __builtin_amdgcn_sched_barrier(0);
    body(a1h, a1l, rd + 1);
  }

  // ---- tail: 16 lists/row x top-3 -> candidates -> exact rescore
  #pragma unroll
  for (int ns = 0; ns < 2; ++ns) {
    int row = ns * 16 + lc;
    int base = row * 48 + (wv * 4 + lg) * 3;
    tv[base + 0] = t1v[ns]; ti[base + 0] = t1i[ns];
    tv[base + 1] = t2v[ns]; ti[base + 1] = t2i[ns];
    tv[base + 2] = t3v[ns]; ti[base + 2] = t3i[ns];
  }
  __syncthreads();

  if (tid < 32) {
    int n = n0 + tid;
    float bv = 3.402823466e+38f; int bi = 0x7FFFFFFF;
    for (int e = 0; e < 48; ++e) {
      float v = tv[tid * 48 + e]; int i2 = ti[tid * 48 + e];
      if (v < bv || (v == bv && i2 < bi)) { bv = v; bi = i2; }
    }
    int ci[CAND_MAX]; int cnt = 0;
    float lim = bv + EPS_CAND;
    for (int e = 0; e < 48; ++e) {
      float v = tv[tid * 48 + e];
      if (v <= lim && cnt < CAND_MAX) {
        int x = ti[tid * 48 + e];
        int p = cnt++;
        while (p > 0 && ci[p - 1] > x) { ci[p] = ci[p - 1]; --p; }
        ci[p] = x;
      }
    }
    int kbest = ci[0];
    if (cnt > 1) {
      int b = n / TLEN, t = n - b * TLEN;
      const float* zr = z + (size_t)b * (DIM * TLEN) + t;
      float bestv = 0.f;
      for (int c = 0; c < cnt; ++c) {
        int k = ci[c];
        const float* cr = cb + (size_t)k * DIM;
        float dot = 0.f;
        for (int d = 0; d < DIM; ++d)
          dot = __fmaf_rn(zr[(size_t)d * TLEN], cr[d], dot);
        float tt = __fadd_rn(x2g[n], y2g[k]);
        float dist = __fsub_rn(tt, __fmul_rn(2.0f, dot));
        if (c == 0 || dist < bestv) { bestv = dist; kbest = k; }
      }
    }
    idx_out[n] = kbest;
    codes_out[n] = (float)kbest;
  }
}

// ---------------- ea_scatter: one WAVE per row n — coalesced EA atomics ----
__global__ void ea_scatter_kernel(const unsigned short* __restrict__ zh,
                                  const unsigned short* __restrict__ zl,
                                  const int* __restrict__ idx,
                                  float* __restrict__ ea_out,
                                  float* __restrict__ counts) {
  int n = (blockIdx.x * 256 + threadIdx.x) >> 6;   // wave id == row
  int lane = threadIdx.x & 63;
  int k = idx[n];
  uint32_t h = *(const uint32_t*)(zh + (size_t)n * 128 + lane * 2);
  uint32_t l = *(const uint32_t*)(zl + (size_t)n * 128 + lane * 2);
  float f0 = bf2f((unsigned short)(h & 0xffffu)) + bf2f((unsigned short)(l & 0xffffu));
  float f1 = bf2f((unsigned short)(h >> 16)) + bf2f((unsigned short)(l >> 16));
  float* dst = ea_out + (size_t)k * DIM + lane * 2;
  atomicAdd(dst, 0.01f * f0);
  atomicAdd(dst + 1, 0.01f * f1);
  if (lane == 0) atomicAdd(counts + k, 1.0f);
}

// ---------------- zq_loss (tiled): LDS-staged cb rows, coalesced both sides -
// 375 blocks x 256 thr, 64 n-rows/block. Read cb[idx[n]] rows coalesced
// (512 B/row), write z_q in [B,D,T] order coalesced. Kills the 3M-random-
// gather that cost ~100us in the flat version.
__global__ void zq_loss_kernel(const float* __restrict__ z, const float* __restrict__ cb,
                               const int* __restrict__ idx,
                               float* __restrict__ zq_out, float* __restrict__ loss_ws) {
  __shared__ float qt[64 * 132];
  const int tid = threadIdx.x;
  const int n0 = blockIdx.x * 64;
  {
    int r = tid >> 2, c = tid & 3;
    int k = idx[n0 + r];
    const float4* src = (const float4*)(cb + (size_t)k * DIM) + c * 8;
    float4* dst = (float4*)(qt + r * 132) + c * 8;
    #pragma unroll
    for (int j = 0; j < 8; ++j) dst[j] = src[j];
  }
  __syncthreads();
  int nl = tid & 63, dd = tid >> 6;
  int n = n0 + nl;
  int b = n / TLEN, t = n - b * TLEN;
  float* zqb = zq_out + (size_t)b * (DIM * TLEN) + t;
  const float* zb = z + (size_t)b * (DIM * TLEN) + t;
  float sq = 0.f;
  #pragma unroll
  for (int d = dd; d < DIM; d += 4) {
    float q = qt[nl * 132 + d];
    zqb[(size_t)d * TLEN] = q;
    float diff = zb[(size_t)d * TLEN] - q;
    sq = fmaf(diff, diff, sq);
  }
  #pragma unroll
  for (int m = 1; m <= 32; m <<= 1) sq += __shfl_xor(sq, m);
  __shared__ float ps[4];
  if ((tid & 63) == 0) ps[tid >> 6] = sq;
  __syncthreads();
  if (tid == 0) atomicAdd(loss_ws, ps[0] + ps[1] + ps[2] + ps[3]);
}

// ---------------- cs_rand ----------------
__global__ void cs_rand_kernel(const float* __restrict__ ema_cs, const float* __restrict__ counts,
                               float* __restrict__ cs0, uint32_t* __restrict__ rnd,
                               float* __restrict__ ntot) {
  int k = blockIdx.x * 256 + threadIdx.x;
  float v = 0.99f * ema_cs[k] + 0.01f * counts[k];
  cs0[k] = v;

  uint32_t o0, o1;
  threefry2x32(0u, 42u, 0u, (uint32_t)k, o0, o1);
  uint32_t bits = o0 ^ o1;
  uint32_t hi = bits >> 16, lo = bits & 0xffffu;
  const uint32_t span = 24000u, mult = 23296u;  // 2^32 % 24000
  uint32_t off = ((hi % span) * mult + (lo % span)) % span;
  rnd[k] = off;

  float s = v;
  #pragma unroll
  for (int m = 1; m <= 32; m <<= 1) s += __shfl_xor(s, m);
  __shared__ float ps[4];
  if ((threadIdx.x & 63) == 0) ps[threadIdx.x >> 6] = s;
  __syncthreads();
  if (threadIdx.x == 0) atomicAdd(ntot, ps[0] + ps[1] + ps[2] + ps[3]);
}

// ---------------- finalize ----------------
__global__ void finalize_kernel(const float* __restrict__ z, const float* __restrict__ cs0_ws,
                                const uint32_t* __restrict__ rnd,
                                const float* __restrict__ ntot_ws, const float* __restrict__ loss_ws,
                                float* __restrict__ out) {
  int i = blockIdx.x * 256 + threadIdx.x;   // i < KD
  int k = i >> 7, d = i & (DIM - 1);
  float cs0 = cs0_ws[k];
  float ntot = *ntot_ws;
  float* ea = out + OFF_EA;
  float ea0 = ea[i];
  float csz = (cs0 + 1e-5f) / (ntot + (float)KCB * 1e-5f) * ntot;
  float embed = ea0 / fmaxf(csz, 1e-12f);
  bool dead = cs0 < 2.0f;
  uint32_t rn = rnd[k];
  int bb = (int)(rn / TLEN), tt = (int)(rn % TLEN);
  float sampled = z[(size_t)bb * (DIM * TLEN) + (size_t)d * TLEN + tt];
  out[OFF_CB + i] = dead ? sampled : embed;
  ea[i] = dead ? sampled : ea0;
  if (d == 0) out[OFF_CS + k] = dead ? 1.0f : cs0;
  if (i == 0) out[OFF_LOSS] = (*loss_ws) * (1.0f / (float)BDT);
}

extern "C" void kernel_launch(void* const* d_in, const int* in_sizes, int n_in,
                              void* d_out, int out_size, void* d_ws, size_t ws_size,
                              hipStream_t stream) {
  const float* z      = (const float*)d_in[0];
  const float* cb     = (const float*)d_in[1];
  const float* ema_cs = (const float*)d_in[2];
  const float* ema_ea = (const float*)d_in[3];
  float* out = (float*)d_out;
  float* wsf = (float*)d_ws;

  unsigned short* zh  = (unsigned short*)(out + OUT_ZH);
  unsigned short* zl  = (unsigned short*)(out + OUT_ZL);
  unsigned short* cbh = (unsigned short*)(out + OUT_CBH);
  unsigned short* cbl = (unsigned short*)(out + OUT_CBL);

  hipMemsetAsync(d_ws, 0, (size_t)(16 + 4096) * sizeof(float), stream);

  prep_cb_kernel<<<KCB / 256, 256, 0, stream>>>(cb, cbh, cbl, wsf + WS_Y2);
  prep_z_kernel<<<NPT / 64, 256, 0, stream>>>(z, zh, zl, wsf + WS_X2);
  ea_init_kernel<<<KD / 256, 256, 0, stream>>>(ema_ea, out + OFF_EA);

  mfma_argmin_kernel<<<NPT / 32, 256, 0, stream>>>(zh, zl, cbh, cbl,
                                                   wsf + WS_Y2, wsf + WS_X2,
                                                   z, cb,
                                                   (int*)(wsf + WS_IDX), out + OFF_CODES);

  // ea_scatter reads zh/zl (z_q region) -> MUST run before zq_loss overwrites it
  ea_scatter_kernel<<<NPT * 64 / 256, 256, 0, stream>>>(zh, zl, (int*)(wsf + WS_IDX),
                                                        out + OFF_EA, wsf + WS_COUNTS);
  zq_loss_kernel<<<NPT / 64, 256, 0, stream>>>(z, cb, (int*)(wsf + WS_IDX),
                                               out + OFF_ZQ, wsf + WS_LOSS);
  cs_rand_kernel<<<KCB / 256, 256, 0, stream>>>(ema_cs, wsf + WS_COUNTS,
                                                wsf + WS_CS0, (uint32_t*)(wsf + WS_RAND),
                                                wsf + WS_NTOT);
  finalize_kernel<<<KD / 256, 256, 0, stream>>>(z, wsf + WS_CS0, (uint32_t*)(wsf + WS_RAND),
                                                wsf + WS_NTOT, wsf + WS_LOSS, out);
}

// Round 13
// 295.096 us; speedup vs baseline: 2.0362x; 1.0392x over previous
//
#include <hip/hip_runtime.h>
#include <stdint.h>

// Problem constants
#define KCB 4096
#define DIM 128
#define BSZ 8
#define TLEN 3000
#define NPT 24000            // BSZ*TLEN
#define KD (KCB*DIM)         // 524288
#define BDT (BSZ*DIM*TLEN)   // 3072000

// Output layout (floats, concatenated in reference return order)
#define OFF_ZQ    0
#define OFF_CODES 3072000
#define OFF_LOSS  3096000
#define OFF_CB    3096001
#define OFF_CS    3620289
#define OFF_EA    3624385

// Big scratch in d_out regions that are dead until later kernels:
//   zh/zl  -> z_q region (written by zq_loss AFTER ea_scatter)
//   cbh/cbl-> new_codebook region (written by finalize LAST)
#define OUT_ZH    0
#define OUT_ZL    1536000
#define OUT_CBH   3096004
#define OUT_CBL   3358148

// Workspace layout (float units) — ~560 KB total (proven ws_size >= ~1 MB in R3)
#define WS_LOSS   0
#define WS_NTOT   1
#define WS_COUNTS 16                     // 4096
#define WS_Y2     (WS_COUNTS + 4096)     // 4096
#define WS_X2     (WS_Y2 + 4096)         // 24000
#define WS_CS0    (WS_X2 + 24000)        // 4096
#define WS_RAND   (WS_CS0 + 4096)        // uint32[4096]
#define WS_IDX    (WS_RAND + 4096)       // int32[24000]
#define WS_RCNT   (WS_IDX + 24000)       // int32[1] (+pad to 16)
#define WS_RLIST  (WS_RCNT + 16)         // int32[RCAP*10]: n,cnt,c0..c7
#define RCAP      8192

#define EPS_CAND 2e-3f
#define CAND_MAX 8

typedef __attribute__((ext_vector_type(8))) short bf16x8;
typedef __attribute__((ext_vector_type(4))) float f32x4;
typedef __attribute__((ext_vector_type(4))) int i32x4;

__device__ __forceinline__ unsigned short f2bf(float f) {
  uint32_t u = __float_as_uint(f);
  uint32_t r = (u + 0x7FFFu + ((u >> 16) & 1u)) >> 16;   // RNE
  return (unsigned short)r;
}
__device__ __forceinline__ float bf2f(unsigned short h) {
  return __uint_as_float(((uint32_t)h) << 16);
}

// ---------------- threefry2x32-20 (JAX-compatible) ----------------
__device__ __forceinline__ void threefry2x32(uint32_t k0, uint32_t k1,
                                             uint32_t x0, uint32_t x1,
                                             uint32_t& o0, uint32_t& o1) {
  const uint32_t ks0 = k0, ks1 = k1, ks2 = k0 ^ k1 ^ 0x1BD11BDAu;
  const int r0[4] = {13, 15, 26, 6};
  const int r1[4] = {17, 29, 16, 24};
  x0 += ks0; x1 += ks1;
  #pragma unroll
  for (int i = 0; i < 5; ++i) {
    #pragma unroll
    for (int j = 0; j < 4; ++j) {
      int r = (i & 1) ? r1[j] : r0[j];
      x0 += x1;
      x1 = (x1 << r) | (x1 >> (32 - r));
      x1 ^= x0;
    }
    uint32_t ia = (uint32_t)((i + 1) % 3), ib = (uint32_t)((i + 2) % 3);
    uint32_t a = (ia == 0) ? ks0 : (ia == 1) ? ks1 : ks2;
    uint32_t b = (ib == 0) ? ks0 : (ib == 1) ? ks1 : ks2;
    x0 += a;
    x1 += b + (uint32_t)(i + 1);
  }
  o0 = x0; o1 = x1;
}

// numpy pairwise sum-of-squares, n=128
__device__ __forceinline__ float np_sumsq_128(const float* __restrict__ v) {
  float r[8];
  #pragma unroll
  for (int j = 0; j < 8; ++j) r[j] = __fmul_rn(v[j], v[j]);
  #pragma unroll
  for (int i = 8; i < DIM; i += 8) {
    #pragma unroll
    for (int j = 0; j < 8; ++j)
      r[j] = __fadd_rn(r[j], __fmul_rn(v[i + j], v[i + j]));
  }
  return __fadd_rn(__fadd_rn(__fadd_rn(r[0], r[1]), __fadd_rn(r[2], r[3])),
                   __fadd_rn(__fadd_rn(r[4], r[5]), __fadd_rn(r[6], r[7])));
}

// ---------------- prep_z ----------------
__global__ void prep_z_kernel(const float* __restrict__ z,
                              unsigned short* __restrict__ zh,
                              unsigned short* __restrict__ zl,
                              float* __restrict__ x2) {
  __shared__ float zt[64 * 132];
  const int tid = threadIdx.x;
  const int n0 = blockIdx.x * 64;
  {
    int nl = tid & 63, dd = tid >> 6;
    int n = n0 + nl;
    int b = n / TLEN, t = n - b * TLEN;
    const float* zbase = z + (size_t)b * (DIM * TLEN) + t;
    #pragma unroll
    for (int d = dd; d < DIM; d += 4) zt[nl * 132 + d] = zbase[(size_t)d * TLEN];
  }
  __syncthreads();
  if (tid < 64) x2[n0 + tid] = np_sumsq_128(zt + tid * 132);

  int r = tid >> 2, d0 = (tid & 3) * 32;
  const float* src = zt + r * 132 + d0;
  size_t base = (size_t)(n0 + r) * 128 + d0;
  #pragma unroll
  for (int c = 0; c < 4; ++c) {
    i32x4 wh, wl;
    #pragma unroll
    for (int q = 0; q < 4; ++q) {
      float f0 = src[c * 8 + q * 2], f1 = src[c * 8 + q * 2 + 1];
      unsigned short h0 = f2bf(f0), h1 = f2bf(f1);
      unsigned short l0 = f2bf(f0 - bf2f(h0)), l1 = f2bf(f1 - bf2f(h1));
      wh[q] = (int)((uint32_t)h0 | ((uint32_t)h1 << 16));
      wl[q] = (int)((uint32_t)l0 | ((uint32_t)l1 << 16));
    }
    *(i32x4*)(zh + base + c * 8) = wh;
    *(i32x4*)(zl + base + c * 8) = wl;
  }
}

// ---------------- prep_cb ----------------
__global__ void prep_cb_kernel(const float* __restrict__ cb,
                               unsigned short* __restrict__ cbh,
                               unsigned short* __restrict__ cbl,
                               float* __restrict__ y2) {
  int k = blockIdx.x * 256 + threadIdx.x;
  const float4* row4 = (const float4*)(cb + (size_t)k * DIM);
  float racc[8];
  #pragma unroll
  for (int j = 0; j < 8; ++j) racc[j] = 0.f;
  #pragma unroll 4
  for (int c2 = 0; c2 < 16; ++c2) {
    float4 a = row4[c2 * 2], b = row4[c2 * 2 + 1];
    float f[8] = {a.x, a.y, a.z, a.w, b.x, b.y, b.z, b.w};
    i32x4 wh, wl;
    #pragma unroll
    for (int q = 0; q < 4; ++q) {
      float f0 = f[q * 2], f1 = f[q * 2 + 1];
      unsigned short h0 = f2bf(f0), h1 = f2bf(f1);
      unsigned short l0 = f2bf(f0 - bf2f(h0)), l1 = f2bf(f1 - bf2f(h1));
      wh[q] = (int)((uint32_t)h0 | ((uint32_t)h1 << 16));
      wl[q] = (int)((uint32_t)l0 | ((uint32_t)l1 << 16));
    }
    *(i32x4*)(cbh + (size_t)k * DIM + c2 * 8) = wh;
    *(i32x4*)(cbl + (size_t)k * DIM + c2 * 8) = wl;
    #pragma unroll
    for (int j = 0; j < 8; ++j)
      racc[j] = __fadd_rn(racc[j], __fmul_rn(f[j], f[j]));
  }
  y2[k] = __fadd_rn(__fadd_rn(__fadd_rn(racc[0], racc[1]), __fadd_rn(racc[2], racc[3])),
                    __fadd_rn(__fadd_rn(racc[4], racc[5]), __fadd_rn(racc[6], racc[7])));
}

// ---------------- ea_init ----------------
__global__ void ea_init_kernel(const float* __restrict__ ema_ea, float* __restrict__ out_ea) {
  int i = blockIdx.x * 256 + threadIdx.x;
  out_ea[i] = 0.99f * ema_ea[i];
}

// ---------------- MFMA argmin: z in LDS (read-only, 1 barrier), A reg-dbuf --
// 750 blocks x 256 thr (4 waves), 32 n/block. z hi/lo staged once into
// swizzled LDS (16 KB) — compiler CANNOT drop it (R10-12: z never stayed in
// regs, VGPR=64/88, ~200us/sweep reload floor). Per round/wave: 16 ds_read
// + 8 global A-loads (2-deep reg dbuf) + 24 MFMA, NO per-round barriers.
// Per-lane top-3 over individual k -> cnt==1 done, else flag row for the
// separate rescore kernel (kills the serial in-block tail).
__launch_bounds__(256, 3)
__global__ void mfma_argmin_kernel(const unsigned short* __restrict__ zh,
                                   const unsigned short* __restrict__ zl,
                                   const unsigned short* __restrict__ cbh,
                                   const unsigned short* __restrict__ cbl,
                                   const float* __restrict__ y2g,
                                   const float* __restrict__ x2g,
                                   const float* __restrict__ z,
                                   const float* __restrict__ cb,
                                   int* __restrict__ idx_out,
                                   float* __restrict__ codes_out,
                                   int* __restrict__ rcnt,
                                   int* __restrict__ rlist) {
  __shared__ alignas(16) unsigned short zh_t[32 * 128];   // swizzled [n][chunk]
  __shared__ alignas(16) unsigned short zl_t[32 * 128];
  __shared__ float tv[32 * 48];
  __shared__ int   ti[32 * 48];

  const int tid = threadIdx.x;
  const int wv = tid >> 6, lane = tid & 63;
  const int lg = lane >> 4, lc = lane & 15;
  const int n0 = blockIdx.x * 32;

  // ---- stage z hi/lo into LDS once (chunk = 16B; swizzle cc = c ^ (row&7))
  {
    int r = tid >> 3, c0 = (tid & 7) * 2;
    const i32x4* gh = (const i32x4*)(zh + (size_t)(n0 + r) * 128);
    const i32x4* gl = (const i32x4*)(zl + (size_t)(n0 + r) * 128);
    #pragma unroll
    for (int c = 0; c < 2; ++c) {
      int cc = (c0 + c) ^ (r & 7);
      ((i32x4*)zh_t)[r * 16 + cc] = gh[c0 + c];
      ((i32x4*)zl_t)[r * 16 + cc] = gl[c0 + c];
    }
  }
  __syncthreads();   // the ONLY barrier before the tail

  const unsigned short* ahb = cbh + (size_t)(wv * 16 + lc) * 128 + lg * 8;
  const unsigned short* alb = cbl + (size_t)(wv * 16 + lc) * 128 + lg * 8;

  float t1v[2], t2v[2], t3v[2];
  int   t1i[2], t2i[2], t3i[2];
  #pragma unroll
  for (int ns = 0; ns < 2; ++ns) {
    t1v[ns] = t2v[ns] = t3v[ns] = 3.402823466e+38f;
    t1i[ns] = t2i[ns] = t3i[ns] = 0x7FFFFFFF;
  }

  bf16x8 a0h[4], a0l[4], a1h[4], a1l[4];
  #pragma unroll
  for (int ds = 0; ds < 4; ++ds) {
    a0h[ds] = *(const bf16x8*)(ahb + ds * 32);
    a0l[ds] = *(const bf16x8*)(alb + ds * 32);
  }

  auto body = [&](bf16x8 (&ah)[4], bf16x8 (&al)[4], int rd) {
    const int kb = rd * 64 + wv * 16;
    // z frags for this round from LDS (2-way bank aliasing = free)
    f32x4 acc[2];
    acc[0] = 0.f; acc[1] = 0.f;
    #pragma unroll
    for (int ds = 0; ds < 4; ++ds) {
      #pragma unroll
      for (int ns = 0; ns < 2; ++ns) {
        int row = ns * 16 + lc;
        int cc = (ds * 4 + lg) ^ (row & 7);
        bf16x8 zb_h = *(const bf16x8*)&zh_t[row * 128 + cc * 8];
        bf16x8 zb_l = *(const bf16x8*)&zl_t[row * 128 + cc * 8];
        acc[ns] = __builtin_amdgcn_mfma_f32_16x16x32_bf16(ah[ds], zb_h, acc[ns], 0, 0, 0);
        acc[ns] = __builtin_amdgcn_mfma_f32_16x16x32_bf16(ah[ds], zb_l, acc[ns], 0, 0, 0);
        acc[ns] = __builtin_amdgcn_mfma_f32_16x16x32_bf16(al[ds], zb_h, acc[ns], 0, 0, 0);
      }
    }
    float4 y4 = *(const float4*)(y2g + kb + lg * 4);
    int kbase = kb + lg * 4;
    #pragma unroll
    for (int ns = 0; ns < 2; ++ns) {
      float dv[4];
      dv[0] = fmaf(-2.f, acc[ns][0], y4.x);
      dv[1] = fmaf(-2.f, acc[ns][1], y4.y);
      dv[2] = fmaf(-2.f, acc[ns][2], y4.z);
      dv[3] = fmaf(-2.f, acc[ns][3], y4.w);
      #pragma unroll
      for (int q = 0; q < 4; ++q) {
        float v = dv[q];
        int kidx = kbase + q;
        bool c1 = v < t1v[ns], c2 = v < t2v[ns], c3 = v < t3v[ns];
        float n3v = c2 ? t2v[ns] : (c3 ? v : t3v[ns]);
        int   n3i = c2 ? t2i[ns] : (c3 ? kidx : t3i[ns]);
        float n2v = c1 ? t1v[ns] : (c2 ? v : t2v[ns]);
        int   n2i = c1 ? t1i[ns] : (c2 ? kidx : t2i[ns]);
        t1v[ns] = c1 ? v : t1v[ns]; t1i[ns] = c1 ? kidx : t1i[ns];
        t2v[ns] = n2v; t2i[ns] = n2i;
        t3v[ns] = n3v; t3i[ns] = n3i;
      }
    }
  };

  for (int rd = 0; rd < 64; rd += 2) {
    {
      size_t o = (size_t)(rd + 1) * 8192;
      #pragma unroll
      for (int ds = 0; ds < 4; ++ds) {
        a1h[ds] = *(const bf16x8*)(ahb + o + ds * 32);
        a1l[ds] = *(const bf16x8*)(alb + o + ds * 32);
      }
    }
    __builtin_amdgcn_sched_barrier(0);
    body(a0h, a0l, rd);
    {
      size_t o = (size_t)(rd + 2) * 8192;  // rd=62 -> row 4096 = cbl start (valid, unused)
      #pragma unroll
      for (int ds = 0; ds < 4; ++ds) {
        a0h[ds] = *(const bf16x8*)(ahb + o + ds * 32);
        a0l[ds] = *(const bf16x8*)(alb + o + ds * 32);
      }
    }
    __builtin_amdgcn_sched_barrier(0);
    body(a1h, a1l, rd + 1);
  }

  // ---- tail: 16 lists/row x top-3 -> candidates; cnt>1 rows -> rescore list
  #pragma unroll
  for (int ns = 0; ns < 2; ++ns) {
    int row = ns * 16 + lc;
    int base = row * 48 + (wv * 4 + lg) * 3;
    tv[base + 0] = t1v[ns]; ti[base + 0] = t1i[ns];
    tv[base + 1] = t2v[ns]; ti[base + 1] = t2i[ns];
    tv[base + 2] = t3v[ns]; ti[base + 2] = t3i[ns];
  }
  __syncthreads();

  if (tid < 32) {
    int n = n0 + tid;
    float bv = 3.402823466e+38f; int bi = 0x7FFFFFFF;
    for (int e = 0; e < 48; ++e) {
      float v = tv[tid * 48 + e]; int i2 = ti[tid * 48 + e];
      if (v < bv || (v == bv && i2 < bi)) { bv = v; bi = i2; }
    }
    int ci[CAND_MAX]; int cnt = 0;
    float lim = bv + EPS_CAND;
    for (int e = 0; e < 48; ++e) {
      float v = tv[tid * 48 + e];
      if (v <= lim && cnt < CAND_MAX) {
        int x = ti[tid * 48 + e];
        int p = cnt++;
        while (p > 0 && ci[p - 1] > x) { ci[p] = ci[p - 1]; --p; }
        ci[p] = x;
      }
    }
    if (cnt == 1) {
      idx_out[n] = ci[0];
      codes_out[n] = (float)ci[0];
    } else {
      int slot = atomicAdd(rcnt, 1);
      if (slot < RCAP) {
        int* e = rlist + slot * 10;
        e[0] = n; e[1] = cnt;
        for (int c = 0; c < CAND_MAX; ++c) e[2 + c] = (c < cnt) ? ci[c] : 0;
        idx_out[n] = ci[0];              // preliminary; rescore overwrites
        codes_out[n] = (float)ci[0];
      } else {
        // overflow fallback: exact np-fp32 rescore in place
        int b = n / TLEN, t = n - b * TLEN;
        const float* zr = z + (size_t)b * (DIM * TLEN) + t;
        float bestv = 0.f; int kbest = ci[0];
        for (int c = 0; c < cnt; ++c) {
          int k = ci[c];
          const float* cr = cb + (size_t)k * DIM;
          float dot = 0.f;
          for (int d = 0; d < DIM; ++d)
            dot = __fmaf_rn(zr[(size_t)d * TLEN], cr[d], dot);
          float tt = __fadd_rn(x2g[n], y2g[k]);
          float dist = __fsub_rn(tt, __fmul_rn(2.0f, dot));
          if (c == 0 || dist < bestv) { bestv = dist; kbest = k; }
        }
        idx_out[n] = kbest;
        codes_out[n] = (float)kbest;
      }
    }
  }
}

// ---------------- rescore: exact np-fp32, one wave per flagged row ---------
// lane c < cnt: serial ascending-d FMA dot (bit-exact sgemm order);
// ascending-c min scan (cands pre-sorted ascending k) = first-occurrence.
__global__ void rescore_kernel(const float* __restrict__ z, const float* __restrict__ cb,
                               const float* __restrict__ x2g, const float* __restrict__ y2g,
                               const int* __restrict__ rcnt, const int* __restrict__ rlist,
                               int* __restrict__ idx_out, float* __restrict__ codes_out) {
  int w = (blockIdx.x * 256 + threadIdx.x) >> 6;
  int lane = threadIdx.x & 63;
  int nw = (gridDim.x * 256) >> 6;
  int total = *rcnt; if (total > RCAP) total = RCAP;
  for (int i = w; i < total; i += nw) {
    const int* e = rlist + i * 10;
    int n = e[0], cnt = e[1];
    int b = n / TLEN, t = n - b * TLEN;
    const float* zr = z + (size_t)b * (DIM * TLEN) + t;
    float dist = 3.402823466e+38f;
    int k = e[2 + (lane < cnt ? lane : 0)];
    if (lane < cnt) {
      const float* cr = cb + (size_t)k * DIM;
      float dot = 0.f;
      #pragma unroll 8
      for (int d = 0; d < DIM; ++d)
        dot = __fmaf_rn(zr[(size_t)d * TLEN], cr[d], dot);
      float tt = __fadd_rn(x2g[n], y2g[k]);
      dist = __fsub_rn(tt, __fmul_rn(2.0f, dot));
    }
    float bestv = 0.f; int kbest = 0;
    for (int c = 0; c < cnt; ++c) {
      float v = __shfl(dist, c);
      int kk = __shfl(k, c);
      if (c == 0 || v < bestv) { bestv = v; kbest = kk; }
    }
    if (lane == 0) {
      idx_out[n] = kbest;
      codes_out[n] = (float)kbest;
    }
  }
}

// ---------------- ea_scatter: one WAVE per row n — coalesced EA atomics ----
__global__ void ea_scatter_kernel(const unsigned short* __restrict__ zh,
                                  const unsigned short* __restrict__ zl,
                                  const int* __restrict__ idx,
                                  float* __restrict__ ea_out,
                                  float* __restrict__ counts) {
  int n = (blockIdx.x * 256 + threadIdx.x) >> 6;
  int lane = threadIdx.x & 63;
  int k = idx[n];
  uint32_t h = *(const uint32_t*)(zh + (size_t)n * 128 + lane * 2);
  uint32_t l = *(const uint32_t*)(zl + (size_t)n * 128 + lane * 2);
  float f0 = bf2f((unsigned short)(h & 0xffffu)) + bf2f((unsigned short)(l & 0xffffu));
  float f1 = bf2f((unsigned short)(h >> 16)) + bf2f((unsigned short)(l >> 16));
  float* dst = ea_out + (size_t)k * DIM + lane * 2;
  atomicAdd(dst, 0.01f * f0);
  atomicAdd(dst + 1, 0.01f * f1);
  if (lane == 0) atomicAdd(counts + k, 1.0f);
}

// ---------------- zq_loss (tiled) ----------------
__global__ void zq_loss_kernel(const float* __restrict__ z, const float* __restrict__ cb,
                               const int* __restrict__ idx,
                               float* __restrict__ zq_out, float* __restrict__ loss_ws) {
  __shared__ float qt[64 * 132];
  const int tid = threadIdx.x;
  const int n0 = blockIdx.x * 64;
  {
    int r = tid >> 2, c = tid & 3;
    int k = idx[n0 + r];
    const float4* src = (const float4*)(cb + (size_t)k * DIM) + c * 8;
    float4* dst = (float4*)(qt + r * 132) + c * 8;
    #pragma unroll
    for (int j = 0; j < 8; ++j) dst[j] = src[j];
  }
  __syncthreads();
  int nl = tid & 63, dd = tid >> 6;
  int n = n0 + nl;
  int b = n / TLEN, t = n - b * TLEN;
  float* zqb = zq_out + (size_t)b * (DIM * TLEN) + t;
  const float* zb = z + (size_t)b * (DIM * TLEN) + t;
  float sq = 0.f;
  #pragma unroll
  for (int d = dd; d < DIM; d += 4) {
    float q = qt[nl * 132 + d];
    zqb[(size_t)d * TLEN] = q;
    float diff = zb[(size_t)d * TLEN] - q;
    sq = fmaf(diff, diff, sq);
  }
  #pragma unroll
  for (int m = 1; m <= 32; m <<= 1) sq += __shfl_xor(sq, m);
  __shared__ float ps[4];
  if ((tid & 63) == 0) ps[tid >> 6] = sq;
  __syncthreads();
  if (tid == 0) atomicAdd(loss_ws, ps[0] + ps[1] + ps[2] + ps[3]);
}

// ---------------- cs_rand ----------------
__global__ void cs_rand_kernel(const float* __restrict__ ema_cs, const float* __restrict__ counts,
                               float* __restrict__ cs0, uint32_t* __restrict__ rnd,
                               float* __restrict__ ntot) {
  int k = blockIdx.x * 256 + threadIdx.x;
  float v = 0.99f * ema_cs[k] + 0.01f * counts[k];
  cs0[k] = v;

  uint32_t o0, o1;
  threefry2x32(0u, 42u, 0u, (uint32_t)k, o0, o1);
  uint32_t bits = o0 ^ o1;
  uint32_t hi = bits >> 16, lo = bits & 0xffffu;
  const uint32_t span = 24000u, mult = 23296u;  // 2^32 % 24000
  uint32_t off = ((hi % span) * mult + (lo % span)) % span;
  rnd[k] = off;

  float s = v;
  #pragma unroll
  for (int m = 1; m <= 32; m <<= 1) s += __shfl_xor(s, m);
  __shared__ float ps[4];
  if ((threadIdx.x & 63) == 0) ps[threadIdx.x >> 6] = s;
  __syncthreads();
  if (threadIdx.x == 0) atomicAdd(ntot, ps[0] + ps[1] + ps[2] + ps[3]);
}

// ---------------- finalize ----------------
__global__ void finalize_kernel(const float* __restrict__ z, const float* __restrict__ cs0_ws,
                                const uint32_t* __restrict__ rnd,
                                const float* __restrict__ ntot_ws, const float* __restrict__ loss_ws,
                                float* __restrict__ out) {
  int i = blockIdx.x * 256 + threadIdx.x;   // i < KD
  int k = i >> 7, d = i & (DIM - 1);
  float cs0 = cs0_ws[k];
  float ntot = *ntot_ws;
  float* ea = out + OFF_EA;
  float ea0 = ea[i];
  float csz = (cs0 + 1e-5f) / (ntot + (float)KCB * 1e-5f) * ntot;
  float embed = ea0 / fmaxf(csz, 1e-12f);
  bool dead = cs0 < 2.0f;
  uint32_t rn = rnd[k];
  int bb = (int)(rn / TLEN), tt = (int)(rn % TLEN);
  float sampled = z[(size_t)bb * (DIM * TLEN) + (size_t)d * TLEN + tt];
  out[OFF_CB + i] = dead ? sampled : embed;
  ea[i] = dead ? sampled : ea0;
  if (d == 0) out[OFF_CS + k] = dead ? 1.0f : cs0;
  if (i == 0) out[OFF_LOSS] = (*loss_ws) * (1.0f / (float)BDT);
}

extern "C" void kernel_launch(void* const* d_in, const int* in_sizes, int n_in,
                              void* d_out, int out_size, void* d_ws, size_t ws_size,
                              hipStream_t stream) {
  const float* z      = (const float*)d_in[0];
  const float* cb     = (const float*)d_in[1];
  const float* ema_cs = (const float*)d_in[2];
  const float* ema_ea = (const float*)d_in[3];
  float* out = (float*)d_out;
  float* wsf = (float*)d_ws;

  unsigned short* zh  = (unsigned short*)(out + OUT_ZH);
  unsigned short* zl  = (unsigned short*)(out + OUT_ZL);
  unsigned short* cbh = (unsigned short*)(out + OUT_CBH);
  unsigned short* cbl = (unsigned short*)(out + OUT_CBL);

  hipMemsetAsync(d_ws, 0, (size_t)(16 + 4096) * sizeof(float), stream);
  hipMemsetAsync(wsf + WS_RCNT, 0, 16 * sizeof(float), stream);

  prep_cb_kernel<<<KCB / 256, 256, 0, stream>>>(cb, cbh, cbl, wsf + WS_Y2);
  prep_z_kernel<<<NPT / 64, 256, 0, stream>>>(z, zh, zl, wsf + WS_X2);
  ea_init_kernel<<<KD / 256, 256, 0, stream>>>(ema_ea, out + OFF_EA);

  mfma_argmin_kernel<<<NPT / 32, 256, 0, stream>>>(zh, zl, cbh, cbl,
                                                   wsf + WS_Y2, wsf + WS_X2,
                                                   z, cb,
                                                   (int*)(wsf + WS_IDX), out + OFF_CODES,
                                                   (int*)(wsf + WS_RCNT), (int*)(wsf + WS_RLIST));
  rescore_kernel<<<64, 256, 0, stream>>>(z, cb, wsf + WS_X2, wsf + WS_Y2,
                                         (const int*)(wsf + WS_RCNT), (const int*)(wsf + WS_RLIST),
                                         (int*)(wsf + WS_IDX), out + OFF_CODES);

  // ea_scatter reads zh/zl (z_q region) -> MUST run before zq_loss overwrites it
  ea_scatter_kernel<<<NPT * 64 / 256, 256, 0, stream>>>(zh, zl, (int*)(wsf + WS_IDX),
                                                        out + OFF_EA, wsf + WS_COUNTS);
  zq_loss_kernel<<<NPT / 64, 256, 0, stream>>>(z, cb, (int*)(wsf + WS_IDX),
                                               out + OFF_ZQ, wsf + WS_LOSS);
  cs_rand_kernel<<<KCB / 256, 256, 0, stream>>>(ema_cs, wsf + WS_COUNTS,
                                                wsf + WS_CS0, (uint32_t*)(wsf + WS_RAND),
                                                wsf + WS_NTOT);
  finalize_kernel<<<KD / 256, 256, 0, stream>>>(z, wsf + WS_CS0, (uint32_t*)(wsf + WS_RAND),
                                                wsf + WS_NTOT, wsf + WS_LOSS, out);
}